// Round 7
// baseline (5087.318 us; speedup 1.0000x reference)
//
#include <hip/hip_runtime.h>

typedef unsigned int u32;
typedef unsigned long long u64;
typedef unsigned short u16;
typedef short bfrag __attribute__((ext_vector_type(8)));   // 8 x bf16 (4 VGPR)
typedef float f4 __attribute__((ext_vector_type(4)));
typedef u32 u32x4 __attribute__((ext_vector_type(4)));
typedef u32 u32x2 __attribute__((ext_vector_type(2)));

#define HID 512
#define SEQT 1024
#define NIN 10
#define NC 9
#define NCL 16          // clusters (bid>>4)
#define MB  16          // batch rows per cluster
#define KSN 17          // 16 x (K=32 over H) + 1 x (x|1|pad) built locally
#define LROW 516        // LDS panel row stride u16 (2-way bank alias only)

#define WPACK_U16 (16*4*2*KSN*64*8)
#define WPACK_BYTES (WPACK_U16*2)
#define HEX_U32 (NCL*2*MB*HID)     // tagged dwords: (bf16 h << 16) | tag
#define HEX_BYTES (HEX_U32*4)

__device__ __forceinline__ u16 f2b(float f){
  u32 u = __float_as_uint(f);
  return (u16)((u + 0x7fffu + ((u>>16)&1u)) >> 16);   // RNE
}
__device__ __forceinline__ float b2f(u16 b){ return __uint_as_float(((u32)b)<<16); }
__device__ __forceinline__ float sigm(float x){ return 1.f/(1.f+__expf(-x)); }
__device__ __forceinline__ float tanh_(float x){ float e=__expf(2.f*x); return 1.f - 2.f/(e+1.f); }

// ---- system-scope (sc0 sc1) — the only scope proven cross-XCD coherent for
// plain ld/st on gfx950 (r3 pass; sc0=SE r4 FAIL; sc1=dev r5 FAIL).
// r2 lesson: inline-asm vmem is untracked by SIInsertWaitcnts — explicit
// s_waitcnt + sched_barrier(0) at every drain-before-use.
__device__ __forceinline__ void st32_sys(u64 base, u32 off, u32 v){
  asm volatile("global_store_dword %0, %1, %2 sc0 sc1" :: "v"(off), "v"(v), "s"(base) : "memory");
}

// ---------------- pack W_hh/W_ih/bias into MFMA B-fragment order ----------------
// (unchanged since round 1 — proven)
__global__ void pack_kernel(const float* __restrict__ W_ih, const float* __restrict__ W_hh,
                            const float* __restrict__ b_ih, const float* __restrict__ b_hh,
                            u16* __restrict__ Wpack)
{
  int tid = blockIdx.x*256 + threadIdx.x;
  if (tid >= 16*4*2*KSN*64) return;
  int lane = tid & 63;
  int rest = tid >> 6;
  int ks = rest % KSN; rest /= KSN;
  int p = rest & 1; rest >>= 1;
  int w = rest & 3; rest >>= 2;
  int g = rest;                       // 0..15
  int c2 = lane & 15;
  int kb = lane >> 4;
  int j = g*32 + w*8 + (c2 & 7);
  int gate = (p ? 2 : 0) + (c2 >= 8 ? 1 : 0);   // i,f,g,o = 0,1,2,3
  int R = gate*HID + j;

  union { u16 s[8]; bfrag v; } o;
  if (ks < 16) {
    const float* src = W_hh + (size_t)R*HID + ks*32 + kb*8;
    #pragma unroll
    for (int e=0;e<8;e++) o.s[e] = f2b(src[e]);
  } else {
    #pragma unroll
    for (int e=0;e<8;e++) {
      int k = kb*8 + e;
      float v = (k < NIN) ? W_ih[(size_t)R*NIN + k] : (k==NIN ? (b_ih[R]+b_hh[R]) : 0.f);
      o.s[e] = f2b(v);
    }
  }
  *(bfrag*)(Wpack + (size_t)tid*8) = o.v;
}

// ---------------- init exchange buffers ----------------
// zero = (h=0, tag=0): buffer0 is valid generation 0; buffer1 zeros have tag 0 != 1.
__global__ void init_kernel(u32* __restrict__ hexw)
{
  int tid = blockIdx.x*256 + threadIdx.x;
  if (tid < HEX_U32) hexw[tid] = 0;
}

// poll helpers: literal chunk index only (keeps gof/lof in registers)
#define PISS(i, vi) \
  if (pend & (1u<<(i))) { \
    asm volatile("global_load_dwordx4 %0, %1, %2 sc0 sc1" \
                 : "=&v"(vi) : "v"(gof[i]), "s"(cur) : "memory"); }
#define PCHK(i, vi) \
  if (pend & (1u<<(i))) { \
    if ((((vi[0]^tg)|(vi[1]^tg)|(vi[2]^tg)|(vi[3]^tg)) & 0xffffu) == 0u) { \
      u32x2 pk = { (vi[0]>>16) | (vi[1]&0xffff0000u), (vi[2]>>16) | (vi[3]&0xffff0000u) }; \
      *(u32x2*)((char*)panb + lof[i]) = pk; \
      pend &= ~(1u<<(i)); } }

// ---------------- persistent LSTM kernel ----------------
// grid = 256 blocks (1/CU), 256 threads (4 waves). cluster = bid>>4, rank g.
// Tag-in-data exchange: no flags, no drains, one barrier per step.
__global__ __launch_bounds__(256, 1) void lstm_kernel(
    const float* __restrict__ inputs, const float* __restrict__ lin_W,
    const float* __restrict__ lin_b, const u16* __restrict__ Wpack,
    u32* __restrict__ hexw, float* __restrict__ out)
{
  const int bid = blockIdx.x;
  const int cl = bid >> 4;
  const int g = bid & 15;
  const int tid = threadIdx.x;
  const int w = tid >> 6;
  const int lane = tid & 63;
  const int c2 = lane & 15;
  const int kb = lane >> 4;
  const int jb = g*32 + w*8;
  const bool lowhalf = (c2 < 8);
  const int vb = cl*MB + g;              // batch row / output row

  __shared__ __align__(16) u16 panel[2][MB*LROW];   // double-buffered h panel (bf16)

  // persistent B-fragments: 2 ntiles x 17 ksteps
  bfrag wf0[KSN], wf1[KSN];
  {
    const u16* base = Wpack + ((size_t)(g*4+w)*2)*KSN*64*8;
    #pragma unroll
    for (int ks=0;ks<KSN;ks++) wf0[ks] = *(const bfrag*)(base + ((size_t)ks*64 + lane)*8);
    #pragma unroll
    for (int ks=0;ks<KSN;ks++) wf1[ks] = *(const bfrag*)(base + ((size_t)(KSN+ks)*64 + lane)*8);
  }
  float lw[3][8]; float lb[3];
  if (w < 3) {
    #pragma unroll
    for (int cc=0;cc<3;cc++){
      int cls = w*3+cc;
      lb[cc] = lin_b[cls];
      #pragma unroll
      for (int e=0;e<8;e++) lw[cc][e] = lin_W[(size_t)cls*HID + lane*8 + e];
    }
  }

  float cst[4] = {0.f,0.f,0.f,0.f};

  const u64 ex0 = (u64)(hexw + (size_t)(cl*2+0)*MB*HID);
  const u64 ex1 = (u64)(hexw + (size_t)(cl*2+1)*MB*HID);

  // poll chunks: 2048 x 16B (4 tagged cols); 8 per thread
  u32 gof[8], lof[8], pend0 = 0;
  #pragma unroll
  for (int i=0;i<8;i++){
    u32 c = (u32)tid + (u32)i*256u;
    u32 row = c >> 7, rem = c & 127u;
    gof[i] = row*2048u + rem*16u;
    lof[i] = row*(LROW*2u) + rem*8u;
    if ((int)(rem >> 3) != g) pend0 |= (1u<<i);     // own-block cols come via LDS self-write
  }

  // panel[0]: own-block cols never polled -> pre-zero (h_0 = 0)
  for (int i = tid; i < MB*LROW; i += 256) panel[0][i] = 0;

  const float* xrow = inputs + (size_t)(cl*MB + c2)*SEQT*NIN;   // batch row c2

  for (int t = 0; t < SEQT; ++t) {
    const u64 cur = (t & 1) ? ex1 : ex0;
    const u64 nxt = (t & 1) ? ex0 : ex1;
    const u32 tg  = (u32)t;
    const u32 tgn = (u32)(t+1);
    u16* panb = &panel[t&1][0];

    // ---- build local x|1 fragment for step t (cached loads)
    union { u32 u[4]; bfrag v; } xu;
    xu.u[0]=0; xu.u[1]=0; xu.u[2]=0; xu.u[3]=0;
    {
      const float* p = xrow + (size_t)t*NIN;
      if (kb == 0) {
        #pragma unroll
        for (int q=0;q<4;q++) xu.u[q] = (u32)f2b(p[2*q]) | ((u32)f2b(p[2*q+1])<<16);
      } else if (kb == 1) {
        xu.u[0] = (u32)f2b(p[8]) | ((u32)f2b(p[9])<<16);
        xu.u[1] = 0x3F80u;                 // k=10 -> 1.0 (bias column)
      }
    }

    // ---- poll remote panel chunks until tag == t, commit to LDS as they land
    {
      u32 pend = pend0;
      u32x4 v0,v1,v2,v3,v4,v5,v6,v7;
      for (int gq = 0; pend && gq < 20000; ++gq) {
        PISS(0,v0) PISS(1,v1) PISS(2,v2) PISS(3,v3)
        PISS(4,v4) PISS(5,v5) PISS(6,v6) PISS(7,v7)
        asm volatile("s_waitcnt vmcnt(0)" ::: "memory");
        __builtin_amdgcn_sched_barrier(0);
        PCHK(0,v0) PCHK(1,v1) PCHK(2,v2) PCHK(3,v3)
        PCHK(4,v4) PCHK(5,v5) PCHK(6,v6) PCHK(7,v7)
      }
    }
    __syncthreads();                       // S1: panel[t&1] complete

    // row-g h for the logits (registers)
    bfrag hx;
    if (w < 3) hx = *(const bfrag*)&panb[g*LROW + lane*8];

    // ---- gates = [h | x,1] @ Wpack^T   (f32 accum)
    f4 acc0 = {0.f,0.f,0.f,0.f}, acc1 = {0.f,0.f,0.f,0.f};
    #pragma unroll
    for (int ks=0;ks<16;ks++){
      bfrag av = *(const bfrag*)&panb[c2*LROW + ks*32 + kb*8];
      acc0 = __builtin_amdgcn_mfma_f32_16x16x32_bf16(av, wf0[ks], acc0, 0,0,0);
      acc1 = __builtin_amdgcn_mfma_f32_16x16x32_bf16(av, wf1[ks], acc1, 0,0,0);
    }
    acc0 = __builtin_amdgcn_mfma_f32_16x16x32_bf16(xu.v, wf0[16], acc0, 0,0,0);
    acc1 = __builtin_amdgcn_mfma_f32_16x16x32_bf16(xu.v, wf1[16], acc1, 0,0,0);

    // ---- activations. lanes c2<8: acc0=i, acc1=g ; c2>=8: acc0=f, acc1=o.
    u16 hb[4];
    #pragma unroll
    for (int r=0;r<4;r++){
      float a0 = sigm(acc0[r]);
      float a1 = lowhalf ? tanh_(acc1[r]) : sigm(acc1[r]);
      float p0 = __shfl_xor(a0, 8, 64);
      float p1 = __shfl_xor(a1, 8, 64);
      float ii = lowhalf ? a0 : p0;
      float ff = lowhalf ? p0 : a0;
      float gg = lowhalf ? a1 : p1;
      float oo = lowhalf ? p1 : a1;
      float cn = ff*cst[r] + ii*gg;
      cst[r] = cn;
      hb[r] = f2b(oo * tanh_(cn));
    }

    // ---- publish tagged gen t+1 (fire-and-forget: no drain, no flag)
    // halves split rows: c2<8 -> rows kb*4+{0,1}; c2>=8 -> rows kb*4+{2,3}
    {
      int col = jb + (c2 & 7);
      u32 rowa = (u32)(kb*4 + (lowhalf ? 0 : 2));
      u16 slo = lowhalf ? hb[0] : hb[2];
      u16 shi = lowhalf ? hb[1] : hb[3];
      u32 cb4 = (u32)(col*4);
      st32_sys(nxt, rowa*2048u + cb4,        ((u32)slo<<16) | tgn);
      st32_sys(nxt, rowa*2048u + 2048u + cb4, ((u32)shi<<16) | tgn);
      // self-write own cols into the next LDS panel (skipped by our poll)
      u16* pn = &panel[(t+1)&1][0];
      pn[rowa*LROW + col]     = slo;
      pn[(rowa+1)*LROW + col] = shi;
    }

    // ---- logits out[t-1] = lin(h_t[row g])  (stores overlap the next poll's RT)
    if (w < 3 && t > 0) {
      float hv[8];
      #pragma unroll
      for (int e=0;e<8;e++) hv[e] = b2f((u16)hx[e]);
      #pragma unroll
      for (int cc=0;cc<3;cc++){
        float s = 0.f;
        #pragma unroll
        for (int e=0;e<8;e++) s += hv[e]*lw[cc][e];
        #pragma unroll
        for (int off=1;off<64;off<<=1) s += __shfl_xor(s, off, 64);
        if (lane == 0)
          out[((size_t)vb*SEQT + (t-1))*NC + (w*3+cc)] = s + lb[cc];
      }
    }
  }

  // ---- epilogue: out[SEQT-1] = lin(h_SEQT[row g]); gen SEQT lives in ex0
  if (w < 3) {
    u32 ge0 = (u32)(g*2048 + (lane*2)*16);
    u32 ge1 = ge0 + 16u;
    u32x4 e0, e1;
    u32 pend = 3u;
    const u32 tg = (u32)SEQT;
    for (int gq = 0; pend && gq < 20000; ++gq) {
      if (pend & 1u)
        asm volatile("global_load_dwordx4 %0, %1, %2 sc0 sc1"
                     : "=&v"(e0) : "v"(ge0), "s"(ex0) : "memory");
      if (pend & 2u)
        asm volatile("global_load_dwordx4 %0, %1, %2 sc0 sc1"
                     : "=&v"(e1) : "v"(ge1), "s"(ex0) : "memory");
      asm volatile("s_waitcnt vmcnt(0)" ::: "memory");
      __builtin_amdgcn_sched_barrier(0);
      if ((pend & 1u) && ((((e0[0]^tg)|(e0[1]^tg)|(e0[2]^tg)|(e0[3]^tg)) & 0xffffu)==0u)) pend &= ~1u;
      if ((pend & 2u) && ((((e1[0]^tg)|(e1[1]^tg)|(e1[2]^tg)|(e1[3]^tg)) & 0xffffu)==0u)) pend &= ~2u;
    }
    float hv[8];
    #pragma unroll
    for (int e=0;e<4;e++){
      hv[e]   = __uint_as_float(e0[e] & 0xffff0000u);
      hv[4+e] = __uint_as_float(e1[e] & 0xffff0000u);
    }
    #pragma unroll
    for (int cc=0;cc<3;cc++){
      float s = 0.f;
      #pragma unroll
      for (int e=0;e<8;e++) s += hv[e]*lw[cc][e];
      #pragma unroll
      for (int off=1;off<64;off<<=1) s += __shfl_xor(s, off, 64);
      if (lane == 0)
        out[((size_t)vb*SEQT + (SEQT-1))*NC + (w*3+cc)] = s + lb[cc];
    }
  }
}

extern "C" void kernel_launch(void* const* d_in, const int* in_sizes, int n_in,
                              void* d_out, int out_size, void* d_ws, size_t ws_size,
                              hipStream_t stream)
{
  const float* inputs = (const float*)d_in[0];
  const float* W_ih   = (const float*)d_in[1];
  const float* W_hh   = (const float*)d_in[2];
  const float* b_ih   = (const float*)d_in[3];
  const float* b_hh   = (const float*)d_in[4];
  const float* lin_W  = (const float*)d_in[5];
  const float* lin_b  = (const float*)d_in[6];

  u16* Wpack = (u16*)d_ws;
  u32* hexw  = (u32*)((char*)d_ws + WPACK_BYTES);

  pack_kernel<<<(16*4*2*KSN*64 + 255)/256, 256, 0, stream>>>(W_ih, W_hh, b_ih, b_hh, Wpack);
  init_kernel<<<(HEX_U32 + 255)/256, 256, 0, stream>>>(hexw);
  lstm_kernel<<<256, 256, 0, stream>>>(inputs, lin_W, lin_b, Wpack, hexw, (float*)d_out);
}